// Round 3
// baseline (251.991 us; speedup 1.0000x reference)
//
#include <hip/hip_runtime.h>
#include <math.h>

#define BATCH 4096
#define NPTS  2048
#define THREADS 256
#define BPB 4                    // batches per persistent block
#define GRID (BATCH / BPB)       // 1024 blocks = 4 blocks/CU, all resident

typedef float f32x4 __attribute__((ext_vector_type(4)));

__device__ __forceinline__ f32x4 ntload(const f32x4* p) {
    return __builtin_nontemporal_load(p);
}

// accumulate one point: h[c*3+d] += src_c * (m * tgt_d)
#define ACC(sx, sy, sz, tx, ty, tz, mm) do {                                   \
    float d0 = (mm) * (tx), d1 = (mm) * (ty), d2 = (mm) * (tz);                \
    h[0] = fmaf((sx), d0, h[0]); h[1] = fmaf((sx), d1, h[1]); h[2] = fmaf((sx), d2, h[2]); \
    h[3] = fmaf((sy), d0, h[3]); h[4] = fmaf((sy), d1, h[4]); h[5] = fmaf((sy), d2, h[5]); \
    h[6] = fmaf((sz), d0, h[6]); h[7] = fmaf((sz), d1, h[7]); h[8] = fmaf((sz), d2, h[8]); \
} while (0)

// One half-batch = one 4-point group per thread: mask quad + 3 src quads + 3 tgt quads.
#define DECL_HALF(P) f32x4 P##m, P##sa, P##sb, P##sc, P##ta, P##tb, P##tc;

#define LOAD_HALF(P, bb, g) do {                                               \
    const f32x4* s4_ = (const f32x4*)(src  + (size_t)(bb) * (NPTS * 3));       \
    const f32x4* t4_ = (const f32x4*)(tgt  + (size_t)(bb) * (NPTS * 3));       \
    const f32x4* m4_ = (const f32x4*)(mask + (size_t)(bb) * NPTS);             \
    const int g_ = (g);                                                        \
    P##m  = ntload(&m4_[g_]);                                                  \
    P##sa = ntload(&s4_[3 * g_ + 0]);                                          \
    P##sb = ntload(&s4_[3 * g_ + 1]);                                          \
    P##sc = ntload(&s4_[3 * g_ + 2]);                                          \
    P##ta = ntload(&t4_[3 * g_ + 0]);                                          \
    P##tb = ntload(&t4_[3 * g_ + 1]);                                          \
    P##tc = ntload(&t4_[3 * g_ + 2]);                                          \
} while (0)

#define FMA_HALF(P) do {                                                       \
    ACC(P##sa.x, P##sa.y, P##sa.z, P##ta.x, P##ta.y, P##ta.z, P##m.x);         \
    ACC(P##sa.w, P##sb.x, P##sb.y, P##ta.w, P##tb.x, P##tb.y, P##m.y);         \
    ACC(P##sb.z, P##sb.w, P##sc.x, P##tb.z, P##tb.w, P##tc.x, P##m.z);         \
    ACC(P##sc.y, P##sc.z, P##sc.w, P##tc.y, P##tc.z, P##tc.w, P##m.w);         \
} while (0)

// fp64 Jacobi eigensolve of H^T H + Kabsch rotation. noinline: one code copy
// (4 call sites), scalar args keep everything in registers (no byref scratch,
// no runtime-indexed arrays anywhere -- round-1 lesson).
__device__ __attribute__((noinline))
void solve_one(float f0, float f1, float f2, float f3, float f4, float f5,
               float f6, float f7, float f8, float* __restrict__ o)
{
    double H[3][3] = {{(double)f0, (double)f1, (double)f2},
                      {(double)f3, (double)f4, (double)f5},
                      {(double)f6, (double)f7, (double)f8}};

    double A[3][3];
#pragma unroll
    for (int i = 0; i < 3; ++i)
#pragma unroll
        for (int j = 0; j < 3; ++j)
            A[i][j] = H[0][i] * H[0][j] + H[1][i] * H[1][j] + H[2][i] * H[2][j];

    double V[3][3] = {{1, 0, 0}, {0, 1, 0}, {0, 0, 1}};

    for (int sweep = 0; sweep < 6; ++sweep) {
#pragma unroll
        for (int r = 0; r < 3; ++r) {
            // compile-time (p,q,k) per r: (0,1,2), (0,2,1), (1,2,0)
            const int p = (r == 2) ? 1 : 0;
            const int q = (r == 0) ? 1 : 2;
            const int k = (r == 0) ? 2 : ((r == 1) ? 1 : 0);
            double apq = A[p][q];
            if (fabs(apq) > 1e-300) {
                double theta = (A[q][q] - A[p][p]) / (2.0 * apq);
                double tt = 1.0 / (fabs(theta) + sqrt(theta * theta + 1.0));
                if (theta < 0.0) tt = -tt;
                double c = 1.0 / sqrt(tt * tt + 1.0);
                double s = tt * c;
                double app = A[p][p], aqq = A[q][q];
                A[p][p] = app - tt * apq;
                A[q][q] = aqq + tt * apq;
                A[p][q] = A[q][p] = 0.0;
                double akp = A[k][p], akq = A[k][q];
                A[k][p] = A[p][k] = c * akp - s * akq;
                A[k][q] = A[q][k] = s * akp + c * akq;
#pragma unroll
                for (int i = 0; i < 3; ++i) {
                    double vip = V[i][p], viq = V[i][q];
                    V[i][p] = c * vip - s * viq;
                    V[i][q] = s * vip + c * viq;
                }
            }
        }
    }

    // Branch-free eigen-column extraction (value selects only).
    const double d0 = A[0][0], d1 = A[1][1], d2 = A[2][2];
    const bool g01 = (d0 >= d1);
    const bool g02 = (d0 >= d2);
    const bool g12 = (d1 >= d2);
    const bool l0 = g01 && g02;
    const bool l1 = (!g01) && g12;

    double v0[3], v1[3];
#pragma unroll
    for (int i = 0; i < 3; ++i) {
        const double c0 = V[i][0], c1 = V[i][1], c2 = V[i][2];
        v0[i] = l0 ? c0 : (l1 ? c1 : c2);
        const double s_l0 = g12 ? c1 : c2;
        const double s_l1 = g02 ? c0 : c2;
        const double s_l2 = g01 ? c0 : c1;
        v1[i] = l0 ? s_l0 : (l1 ? s_l1 : s_l2);
    }

    double b0[3], b1[3];
#pragma unroll
    for (int r = 0; r < 3; ++r) {
        b0[r] = H[r][0] * v0[0] + H[r][1] * v0[1] + H[r][2] * v0[2];
        b1[r] = H[r][0] * v1[0] + H[r][1] * v1[1] + H[r][2] * v1[2];
    }
    double n0 = b0[0] * b0[0] + b0[1] * b0[1] + b0[2] * b0[2];
    double inv0 = 1.0 / sqrt(fmax(n0, 1e-300));
    double u0[3] = {b0[0] * inv0, b0[1] * inv0, b0[2] * inv0};
    double d01 = u0[0] * b1[0] + u0[1] * b1[1] + u0[2] * b1[2];
    double w[3] = {b1[0] - d01 * u0[0], b1[1] - d01 * u0[1], b1[2] - d01 * u0[2]};
    double nw = w[0] * w[0] + w[1] * w[1] + w[2] * w[2];
    double inv1 = 1.0 / sqrt(fmax(nw, 1e-300));
    double u1[3] = {w[0] * inv1, w[1] * inv1, w[2] * inv1};
    double u2[3] = {u0[1] * u1[2] - u0[2] * u1[1],
                    u0[2] * u1[0] - u0[0] * u1[2],
                    u0[0] * u1[1] - u0[1] * u1[0]};
    double vc2[3] = {v0[1] * v1[2] - v0[2] * v1[1],
                     v0[2] * v1[0] - v0[0] * v1[2],
                     v0[0] * v1[1] - v0[1] * v1[0]};

#pragma unroll
    for (int r = 0; r < 3; ++r)
#pragma unroll
        for (int c = 0; c < 3; ++c)
            o[r * 3 + c] = (float)(v0[r] * u0[c] + v1[r] * u1[c] + vc2[r] * u2[c]);
}

// Persistent pipelined kernel: 1024 blocks x 4 batches. Per batch iteration:
//   issue B-half(j) -> FMA A-half(j) [prefetched] -> issue A-half(j+1)
//   -> FMA B-half(j) -> butterfly -> shred -> barrier -> t0 solves batch j.
// A-half(j+1) is in flight across the reduce/barrier/solve tail, so memory
// never drains (round-2's convoy: 4 resident blocks phase-locked, HBM idle
// during every tail -> 63.5us vs ~37us stream floor). shred double-buffered
// by batch parity so waves 1-3 can run ahead while t0 solves.
__global__ __launch_bounds__(THREADS, 4)
void fused_kernel(const float* __restrict__ src, const float* __restrict__ tgt,
                  const float* __restrict__ mask, float* __restrict__ out)
{
    const int t    = threadIdx.x;
    const int b0   = blockIdx.x * BPB;
    const int wid  = t >> 6;
    const int lane = t & 63;

    __shared__ float shred[2][THREADS / 64][9];

    DECL_HALF(A0) DECL_HALF(A1) DECL_HALF(B_)

#define HS(jj, i) (shred[(jj) & 1][0][i] + shred[(jj) & 1][1][i] + \
                   shred[(jj) & 1][2][i] + shred[(jj) & 1][3][i])

#define ITER(CUR, NXT, jj, DO_PREF) do {                                       \
    LOAD_HALF(B_, b0 + (jj), t + 256);                                         \
    float h[9] = {0.f, 0.f, 0.f, 0.f, 0.f, 0.f, 0.f, 0.f, 0.f};               \
    FMA_HALF(CUR);                                                             \
    if (DO_PREF) { LOAD_HALF(NXT, b0 + (jj) + 1, t); }                         \
    FMA_HALF(B_);                                                              \
    _Pragma("unroll")                                                          \
    for (int off = 32; off > 0; off >>= 1) {                                   \
        _Pragma("unroll")                                                      \
        for (int i = 0; i < 9; ++i) h[i] += __shfl_down(h[i], off);            \
    }                                                                          \
    if (lane == 0) {                                                           \
        _Pragma("unroll")                                                      \
        for (int i = 0; i < 9; ++i) shred[(jj) & 1][wid][i] = h[i];            \
    }                                                                          \
    __syncthreads();                                                           \
    if (t == 0) {                                                              \
        solve_one(HS(jj, 0), HS(jj, 1), HS(jj, 2),                             \
                  HS(jj, 3), HS(jj, 4), HS(jj, 5),                             \
                  HS(jj, 6), HS(jj, 7), HS(jj, 8),                             \
                  out + (size_t)(b0 + (jj)) * 9);                              \
    }                                                                          \
} while (0)

    LOAD_HALF(A0, b0, t);      // prologue: A-half of batch 0
    ITER(A0, A1, 0, 1);
    ITER(A1, A0, 1, 1);
    ITER(A0, A1, 2, 1);
    ITER(A1, A0, 3, 0);

#undef ITER
#undef HS
}

extern "C" void kernel_launch(void* const* d_in, const int* in_sizes, int n_in,
                              void* d_out, int out_size, void* d_ws, size_t ws_size,
                              hipStream_t stream) {
    const float* src  = (const float*)d_in[0];
    const float* tgt  = (const float*)d_in[1];
    // d_in[2] (kpt_src_mask) is unused by the reference
    const float* mask = (const float*)d_in[3];
    float* out = (float*)d_out;

    fused_kernel<<<GRID, THREADS, 0, stream>>>(src, tgt, mask, out);
}